// Round 14
// baseline (20.305 us; speedup 1.0000x reference)
//
#include <hip/hip_runtime.h>
#include <hip/hip_bf16.h>

typedef short short8 __attribute__((ext_vector_type(8)));
typedef float f32x4 __attribute__((ext_vector_type(4)));

union FragAB { unsigned long long l[2]; int i[4]; short8 v; };

// Round-14 = round-13 base + tile-pairing: each block stages one 64p x-panel
// and computes TWO (h,sy) output tiles from it (e2 = 0,1). Grid 512 = exactly
// 2 blocks/CU, one generation, no tail; staging front-end work halves.
//
// Swapped-operand formulation: D[p=(b,f), j] = sum_i A[p,i] * B[i,j]
//   A[p,i] = bf16(x[b, sx, i, f])            (Xts rows, k-contiguous)
//   B[i,j] = T[j,i] = wfor[255 + diag - j + i]
//   wfor[q] = krow[q] for q in [0,255], 0 elsewhere (zero-pad = triangular
//   mask AND the diagonal roll-by-one, which switches divisor to j+1-diag).
// Copy s holds wfor shifted +s (wforL[e2][s][q] = wfor[q-s]); reads use
// byte = e2*2688 + s*674 + 2*w00, making every lane's 8-element window
// 8-byte aligned -> B-frag = 2x ds_read_b64.
__global__ __launch_bounds__(256, 3)
void k_fused(const float* __restrict__ x,     // [16,8,256,16]
             const float* __restrict__ kern,  // [4,8,8,256]
             float* __restrict__ out)         // [16,4,8,8,256,16]
{
    __shared__ __align__(16) ushort Xts[64 * 264];      // [p][k], row 528 B
    __shared__ __align__(8)  ushort wforL[2][4][336];   // [e2][shift][q]
    __shared__ float rtab[2][256];

    const int blk = blockIdx.x;             // 0..511
    const int c  = blk & 15;                // hy pair (hy = 2c, 2c+1)
    const int sx = (blk >> 4) & 7;
    const int nt = blk >> 7;                // p-quarter (b-quad)
    const int t = threadIdx.x;

    // ---- minimal wfor build + rtab, for both e2 ----
    #pragma unroll
    for (int e2 = 0; e2 < 2; ++e2) {
        const int hy = 2 * c + e2;
        const int h = hy >> 3, sy = hy & 7;
        const int diag = (sx == sy) ? 1 : 0;
        const float* krow = kern + ((h * 8 + sx) * 8 + sy) * 256;
        float v = krow[t];
        __hip_bfloat16 hv = __float2bfloat16(v);
        ushort u = reinterpret_cast<ushort&>(hv);
        #pragma unroll
        for (int s = 0; s < 4; ++s)
            wforL[e2][s][t + s] = u;            // wforL[e2][s][q] = wfor[q-s]
        if (t < 88) {                           // zero tail q in [256+s, 336)
            #pragma unroll
            for (int s = 0; s < 4; ++s) {
                int q = 256 + s + t;
                if (q < 336) wforL[e2][s][q] = 0;
            }
        }
        if (t < 4) {                            // zero head q in [0, s)
            #pragma unroll
            for (int s = 1; s < 4; ++s)
                if (t < s) wforL[e2][s][t] = 0;
        }
        int denom = t + 1 - diag;
        rtab[e2][t] = (denom > 0) ? (1.0f / (float)denom) : 0.0f;
    }
    // ---- stage + transpose x quarter-slice -> Xts: Xts[bl*16+f][k] ----
    {
        const float4* xbase = reinterpret_cast<const float4*>(x);
        #pragma unroll
        for (int it = 0; it < 8; ++it) {
            int id = it * 256 + t;              // 0..2047
            int fq = id & 3;
            int k2 = (id >> 2) & 127;
            int bl = id >> 9;                   // local b 0..3
            const float4* rowp = xbase + ((size_t)((nt * 4 + bl) * 8 + sx)) * 1024;
            float4 a = rowp[(2 * k2) * 4 + fq];
            float4 cq = rowp[(2 * k2 + 1) * 4 + fq];
            #pragma unroll
            for (int e = 0; e < 4; ++e) {
                float va = (&a.x)[e], vb = (&cq.x)[e];
                __hip_bfloat16 ha = __float2bfloat16(va);
                __hip_bfloat16 hb = __float2bfloat16(vb);
                uint u = (uint)reinterpret_cast<ushort&>(ha) |
                         ((uint)reinterpret_cast<ushort&>(hb) << 16);
                int row = bl * 16 + fq * 4 + e;
                *reinterpret_cast<uint*>(reinterpret_cast<char*>(Xts) + row * 528 + k2 * 4) = u;
            }
        }
    }
    __syncthreads();

    const int lane = t & 63, wid = t >> 6;
    const int laneM = lane & 15, laneG = lane >> 4;
    const int wj0 = wid * 64;                   // wave's j base
    const int kmax = wj0 + 64;                  // triangle skip

    const char* XtsB = reinterpret_cast<const char*>(Xts);
    const char* WB = reinterpret_cast<const char*>(wforL);
    const int abyte = laneM * 528 + laneG * 16;

    #pragma unroll
    for (int e2 = 0; e2 < 2; ++e2) {
        const int hy = 2 * c + e2;
        const int h = hy >> 3, sy = hy & 7;
        const int diag = (sx == sy) ? 1 : 0;

        // B element e (lane) for frag n, step kc: wfor[w00 + kc - 16n + e]
        const int w00 = 255 + diag - wj0 - laneM + 8 * laneG;
        const int s = (laneM - diag + 1) & 3;   // makes (w00+s) % 4 == 0
        const int bB = e2 * 2688 + s * 674 + 2 * w00;

        f32x4 acc[4][4];
        #pragma unroll
        for (int m = 0; m < 4; ++m)
            #pragma unroll
            for (int n = 0; n < 4; ++n)
                acc[m][n] = (f32x4){0.0f, 0.0f, 0.0f, 0.0f};

        for (int kc = 0; kc < kmax; kc += 32) {
            FragAB af[4];
            #pragma unroll
            for (int m = 0; m < 4; ++m) {
                const int4 raw = *reinterpret_cast<const int4*>(
                    XtsB + abyte + m * 8448 + kc * 2);
                af[m].i[0] = raw.x; af[m].i[1] = raw.y;
                af[m].i[2] = raw.z; af[m].i[3] = raw.w;
            }
            FragAB bf[4];
            #pragma unroll
            for (int n = 0; n < 4; ++n) {
                const char* p = WB + bB + kc * 2 - 32 * n;
                bf[n].l[0] = *reinterpret_cast<const unsigned long long*>(p);
                bf[n].l[1] = *reinterpret_cast<const unsigned long long*>(p + 8);
            }
            #pragma unroll
            for (int m = 0; m < 4; ++m)
                #pragma unroll
                for (int n = 0; n < 4; ++n)
                    acc[m][n] = __builtin_amdgcn_mfma_f32_16x16x32_bf16(
                        af[m].v, bf[n].v, acc[m][n], 0, 0, 0);
        }

        // ---- store this e2 tile now; m outer / n inner -> 4 KB runs ----
        #pragma unroll
        for (int m = 0; m < 4; ++m) {
            const int b_ = nt * 4 + m;
            float* obase = out
                + (((size_t)(b_ * 4 + h) * 8 + sx) * 8 + sy) * 4096
                + laneG * 4;
            #pragma unroll
            for (int n = 0; n < 4; ++n) {
                const int j = wj0 + 16 * n + laneM;
                const float rt = rtab[e2][j];
                f32x4 v = acc[m][n] * rt;
                __builtin_nontemporal_store(
                    v, reinterpret_cast<f32x4*>(obase + (size_t)j * 16));
            }
        }
    }
}

extern "C" void kernel_launch(void* const* d_in, const int* in_sizes, int n_in,
                              void* d_out, int out_size, void* d_ws, size_t ws_size,
                              hipStream_t stream) {
    const float* x    = (const float*)d_in[0];   // [16,8,256,16]
    const float* kern = (const float*)d_in[1];   // [4,8,8,256]
    float* out = (float*)d_out;                  // [16,4,8,8,256,16]

    k_fused<<<512, 256, 0, stream>>>(x, kern, out);
}